// Round 2
// 1647.875 us; speedup vs baseline: 1.0269x; 1.0269x over previous
//
#include <hip/hip_runtime.h>
#include <cstddef>
#include <cstdint>

// Problem constants (fixed by reference): B=64, T=128, C=4096, H=32, HS=128
#define NB 64
#define NH 32
#define NT 128
#define NHS 128
#define NC 4096
#define SCALE 0.17677669529663687f  // 32^-0.5
#define SLD 136                      // bf16 leading dim for attention score tile

typedef __bf16 bf16_t;
typedef __bf16 bf16x8 __attribute__((ext_vector_type(8)));
typedef float  f32x4  __attribute__((ext_vector_type(4)));

// Async global->LDS, 16B per lane. LDS dest must be wave-uniform base + lane*16.
__device__ __forceinline__ void load_lds16(const bf16_t* g, bf16_t* l) {
    __builtin_amdgcn_global_load_lds(
        (const __attribute__((address_space(1))) char*)g,
        (__attribute__((address_space(3))) char*)l,
        16, 0, 0);
}

// ---------------------------------------------------------------------------
// Conversion: fp32 -> bf16, 8 elements/thread
// ---------------------------------------------------------------------------
__global__ __launch_bounds__(256) void cvt_bf16_kernel(
    const float* __restrict__ in, bf16_t* __restrict__ out, int n8)
{
    int i = blockIdx.x * 256 + threadIdx.x;
    if (i >= n8) return;
    const float4* p = (const float4*)in + (size_t)i * 2;
    float4 a = p[0], b = p[1];
    bf16x8 o;
    o[0] = (bf16_t)a.x; o[1] = (bf16_t)a.y; o[2] = (bf16_t)a.z; o[3] = (bf16_t)a.w;
    o[4] = (bf16_t)b.x; o[5] = (bf16_t)b.y; o[6] = (bf16_t)b.z; o[7] = (bf16_t)b.w;
    ((bf16x8*)out)[i] = o;
}

// ---------------------------------------------------------------------------
// Conversion + transpose: w [H][C][HS] fp32 -> wT [H][HS][C] bf16.
// ---------------------------------------------------------------------------
__global__ __launch_bounds__(256) void cvt_w_transpose_kernel(
    const float* __restrict__ wq, const float* __restrict__ wk, const float* __restrict__ wv,
    bf16_t* __restrict__ qt, bf16_t* __restrict__ kt, bf16_t* __restrict__ vt)
{
    const float* w; bf16_t* o;
    if (blockIdx.y == 0)      { w = wq; o = qt; }
    else if (blockIdx.y == 1) { w = wk; o = kt; }
    else                      { w = wv; o = vt; }
    const int h   = blockIdx.x >> 7;
    const int rem = blockIdx.x & 127;
    const int c0  = (rem >> 1) * 64;
    const int s0  = (rem & 1) * 64;
    const float* W = w + (size_t)h * NC * NHS;
    bf16_t* O = o + (size_t)h * NHS * NC;

    __shared__ float t[64][65];
    const int tid = threadIdx.x;
    #pragma unroll
    for (int it = 0; it < 16; ++it) {
        int idx = it * 256 + tid;
        int r = idx >> 6, cc = idx & 63;
        t[r][cc] = W[(size_t)(c0 + r) * NHS + s0 + cc];
    }
    __syncthreads();
    #pragma unroll
    for (int it = 0; it < 16; ++it) {
        int idx = it * 256 + tid;
        int sr = idx >> 6, cr = idx & 63;
        O[(size_t)(s0 + sr) * NC + c0 + cr] = (bf16_t)t[cr][sr];
    }
}

// ---------------------------------------------------------------------------
// 256x256 tile GEMM core, K = 4096 (ld = NC for both operands), 8 waves.
// D(256x256) = A(256x4096) * BT(256x4096)^T, bf16 in, fp32 acc.
// Deep pipeline: 2-tile prefetch via global_load_lds, counted vmcnt (never 0
// in steady state), raw s_barrier (no implicit vmcnt(0) drain), XOR-swizzled
// LDS (pre-swizzled global source; linear LDS dest), setprio'd MFMA clusters.
// LDS: 2 buf x (A 32K + B 32K) = 128 KiB -> 1 block/CU, 2 waves/SIMD.
// ---------------------------------------------------------------------------
#define TILE_EL 16384   // 256 rows x 64 cols

__device__ __forceinline__ void gemm256_core(
    const bf16_t* __restrict__ A, const bf16_t* __restrict__ BT, f32x4 acc[8][4])
{
    __shared__ __align__(16) bf16_t As[2 * TILE_EL];
    __shared__ __align__(16) bf16_t Bs[2 * TILE_EL];

    const int tid  = threadIdx.x;
    const int lane = tid & 63;
    const int w    = tid >> 6;
    const int wr   = w >> 2;   // 0..1 (M half)
    const int wc   = w & 3;    // 0..3 (N quarter)

    // --- staging geometry: slab j (64 rows), thread covers 8 contiguous els.
    // LDS is filled LINEARLY (global_load_lds constraint); the global source
    // column is pre-swizzled so LDS slot (r,c) holds element (r, c^swz(r)),
    // swz(r) = (r&7)<<3  (full 8-octet spread -> conflict-free ds_read_b128).
    const int srow  = tid >> 3;                                   // 0..63
    const int scol  = ((tid & 7) * 8) ^ (((tid >> 3) & 7) << 3);  // pre-swizzled
    const int sslot = tid * 8;                                    // elements

    // --- fragment read offsets (elements within one 16384-el tile) ---
    const int frow = lane & 15;
    const int fk   = (lane >> 4) * 8;
    int aoff[2][2][4];   // [ks][mh][q]
    #pragma unroll
    for (int ks = 0; ks < 2; ++ks)
        #pragma unroll
        for (int mh = 0; mh < 2; ++mh)
            #pragma unroll
            for (int q = 0; q < 4; ++q) {
                int r = wr * 128 + mh * 64 + q * 16 + frow;
                aoff[ks][mh][q] = r * 64 + ((ks * 32 + fk) ^ ((r & 7) << 3));
            }
    int boff[2][4];      // [ks][n]
    #pragma unroll
    for (int ks = 0; ks < 2; ++ks)
        #pragma unroll
        for (int n = 0; n < 4; ++n) {
            int r = wc * 64 + n * 16 + frow;
            boff[ks][n] = r * 64 + ((ks * 32 + fk) ^ ((r & 7) << 3));
        }

    // stage one half-tile (128 rows = slabs {2h, 2h+1}), 2 loads/thread
    auto stage = [&](const bf16_t* __restrict__ G, int half, int k0, bf16_t* dst) {
        #pragma unroll
        for (int jj = 0; jj < 2; ++jj) {
            const int j = half * 2 + jj;
            load_lds16(G + (size_t)(j * 64 + srow) * NC + (k0 + scol),
                       dst + j * 4096 + sslot);
        }
    };

    // Prologue: tile0 -> buf0, tile1 -> buf1 (16 loads); confirm tile0 only.
    stage(A,  0, 0, As);           stage(A,  1, 0, As);
    stage(BT, 0, 0, Bs);           stage(BT, 1, 0, Bs);
    stage(A,  0, 64, As + TILE_EL); stage(A,  1, 64, As + TILE_EL);
    stage(BT, 0, 64, Bs + TILE_EL); stage(BT, 1, 64, Bs + TILE_EL);
    asm volatile("s_waitcnt vmcnt(8)" ::: "memory");
    __builtin_amdgcn_s_barrier();
    __builtin_amdgcn_sched_barrier(0);

    for (int t = 0; t < NC / 64; ++t) {
        bf16_t* Ac = As + (t & 1) * TILE_EL;
        bf16_t* Bc = Bs + (t & 1) * TILE_EL;
        const int  kn = t * 64 + 128;          // k0 of tile t+2
        const bool pf = (t < NC / 64 - 2);

        bf16x8 b0[4], b1[4], a[4];
        // ---- phase (mh=0, ks=0): read ALL B frags (both ksteps) + A quarter
        #pragma unroll
        for (int n = 0; n < 4; ++n) b0[n] = *(const bf16x8*)(Bc + boff[0][n]);
        #pragma unroll
        for (int n = 0; n < 4; ++n) b1[n] = *(const bf16x8*)(Bc + boff[1][n]);
        #pragma unroll
        for (int q = 0; q < 4; ++q) a[q] = *(const bf16x8*)(Ac + aoff[0][0][q]);
        __builtin_amdgcn_s_setprio(1);
        #pragma unroll
        for (int q = 0; q < 4; ++q)
            #pragma unroll
            for (int n = 0; n < 4; ++n)
                acc[q][n] = __builtin_amdgcn_mfma_f32_16x16x32_bf16(a[q], b0[n], acc[q][n], 0, 0, 0);
        __builtin_amdgcn_s_setprio(0);
        // b1 reads are not consumed yet -> force completion before B region
        // of buf[cur] is declared free for the tile-(t+2) stage writes.
        asm volatile("s_waitcnt lgkmcnt(0)" ::: "memory");
        __builtin_amdgcn_s_barrier();          // all waves done reading B
        __builtin_amdgcn_sched_barrier(0);

        // ---- phase (mh=1, ks=0): stage B half0 of tile t+2 into freed region
        if (pf) stage(BT, 0, kn, Bc);
        #pragma unroll
        for (int q = 0; q < 4; ++q) a[q] = *(const bf16x8*)(Ac + aoff[0][1][q]);
        __builtin_amdgcn_s_setprio(1);
        #pragma unroll
        for (int q = 0; q < 4; ++q)
            #pragma unroll
            for (int n = 0; n < 4; ++n)
                acc[4 + q][n] = __builtin_amdgcn_mfma_f32_16x16x32_bf16(a[q], b0[n], acc[4 + q][n], 0, 0, 0);
        __builtin_amdgcn_s_setprio(0);

        // ---- phase (mh=0, ks=1): stage B half1 of tile t+2
        if (pf) stage(BT, 1, kn, Bc);
        #pragma unroll
        for (int q = 0; q < 4; ++q) a[q] = *(const bf16x8*)(Ac + aoff[1][0][q]);
        __builtin_amdgcn_s_setprio(1);
        #pragma unroll
        for (int q = 0; q < 4; ++q)
            #pragma unroll
            for (int n = 0; n < 4; ++n)
                acc[q][n] = __builtin_amdgcn_mfma_f32_16x16x32_bf16(a[q], b1[n], acc[q][n], 0, 0, 0);
        __builtin_amdgcn_s_setprio(0);

        // ---- phase (mh=1, ks=1)
        #pragma unroll
        for (int q = 0; q < 4; ++q) a[q] = *(const bf16x8*)(Ac + aoff[1][1][q]);
        __builtin_amdgcn_s_setprio(1);
        #pragma unroll
        for (int q = 0; q < 4; ++q)
            #pragma unroll
            for (int n = 0; n < 4; ++n)
                acc[4 + q][n] = __builtin_amdgcn_mfma_f32_16x16x32_bf16(a[q], b1[n], acc[4 + q][n], 0, 0, 0);
        __builtin_amdgcn_s_setprio(0);

        asm volatile("s_waitcnt lgkmcnt(0)" ::: "memory");
        __builtin_amdgcn_s_barrier();          // all waves done with buf[cur]
        __builtin_amdgcn_sched_barrier(0);
        if (pf) {
            stage(A, 0, kn, Ac); stage(A, 1, kn, Ac);
            // retire exactly tile t+1's 8 loads; keep tile t+2's 8 in flight
            asm volatile("s_waitcnt vmcnt(8)" ::: "memory");
        } else if (t == NC / 64 - 2) {
            asm volatile("s_waitcnt vmcnt(0)" ::: "memory");  // drain tail
        }
        __builtin_amdgcn_s_barrier();          // tile t+1 visible to all waves
        __builtin_amdgcn_sched_barrier(0);
    }
}

// ---------------------------------------------------------------------------
// QKV as ONE GEMM: x[8192,4096] * Wcat[12288,4096]^T.  Wcat = wqT|wkT|wvT
// contiguous ([tensor][h][s][c]).  grid = 1536 blocks (32 mt x 48 nt),
// XCD-chunked swizzle.  q,k stored [bh][t][s]; v stored transposed [bh][s][t].
// ---------------------------------------------------------------------------
__global__ __launch_bounds__(512, 2) void qkv_gemm256_kernel(
    const bf16_t* __restrict__ xb, const bf16_t* __restrict__ wcat,
    bf16_t* __restrict__ q, bf16_t* __restrict__ k, bf16_t* __restrict__ v)
{
    const int bid = blockIdx.x;
    const int wg  = (bid & 7) * 192 + (bid >> 3);   // 1536 = 8 * 192, bijective
    const int mt  = wg / 48;
    const int nt  = wg - mt * 48;
    const int Mb  = mt << 8;
    const int Nb  = nt << 8;

    f32x4 acc[8][4] = {};
    gemm256_core(xb + (size_t)Mb * NC, wcat + (size_t)Nb * NC, acc);

    const int tid = threadIdx.x, lane = tid & 63, w = tid >> 6;
    const int wr = w >> 2, wc = w & 3;
    const int tens = Nb >> 12;                       // 0=q 1=k 2=v (uniform)
    bf16_t* const outp = (tens == 0) ? q : (tens == 1) ? k : v;
    const int colb = Nb + wc * 64 + (lane & 15);
    const int rowb = Mb + wr * 128 + ((lane >> 4) << 2);
    #pragma unroll
    for (int i = 0; i < 8; ++i)
        #pragma unroll
        for (int r = 0; r < 4; ++r) {
            const int m  = rowb + i * 16 + r;
            const int bb = m >> 7, tt = m & 127;
            #pragma unroll
            for (int n = 0; n < 4; ++n) {
                const int ng = colb + n * 16;
                const int hh = (ng >> 7) & 31, ss = ng & 127;
                const size_t base = (size_t)((bb << 5) + hh) << 14;
                if (tens == 2) outp[base + ss * NT  + tt] = (bf16_t)acc[i][n][r];
                else           outp[base + tt * NHS + ss] = (bf16_t)acc[i][n][r];
            }
        }
}

// ---------------------------------------------------------------------------
// Projection as ONE GEMM: attnT[8192,4096] * wp[4096,4096]^T + bp.
// grid = 512 blocks (32 mt x 16 nt), XCD-chunked swizzle.
// ---------------------------------------------------------------------------
__global__ __launch_bounds__(512, 2) void proj_gemm256_kernel(
    const bf16_t* __restrict__ attnT, const bf16_t* __restrict__ wpb,
    const float* __restrict__ bp, float* __restrict__ out)
{
    const int bid = blockIdx.x;
    const int wg  = (bid & 7) * 64 + (bid >> 3);    // 512 = 8 * 64, bijective
    const int mt  = wg >> 4;
    const int nt  = wg & 15;
    const int Mb  = mt << 8;
    const int Nb  = nt << 8;

    f32x4 acc[8][4] = {};
    gemm256_core(attnT + (size_t)Mb * NC, wpb + (size_t)Nb * NC, acc);

    const int tid = threadIdx.x, lane = tid & 63, w = tid >> 6;
    const int wr = w >> 2, wc = w & 3;
    const int colb = Nb + wc * 64 + (lane & 15);
    const int rowb = Mb + wr * 128 + ((lane >> 4) << 2);
    float bias[4];
    #pragma unroll
    for (int n = 0; n < 4; ++n) bias[n] = bp[colb + n * 16];
    #pragma unroll
    for (int i = 0; i < 8; ++i)
        #pragma unroll
        for (int r = 0; r < 4; ++r) {
            const size_t m = (size_t)(rowb + i * 16 + r);
            #pragma unroll
            for (int n = 0; n < 4; ++n)
                out[m * NC + colb + n * 16] = acc[i][n][r] + bias[n];
        }
}

// ---------------------------------------------------------------------------
// MFMA attention per (b,h): S = scale*Q*K^T (MFMA) -> column softmax (query
// axis, fp32) -> O^T[s][t] = sum_u vT[s][u] * P[t][u] (MFMA).
// Writes attnT[b][s][h*T+t] bf16. LDS: 8K As + 8K Bs + 34K S = 50 KB.
// ---------------------------------------------------------------------------
__global__ __launch_bounds__(256) void attn_mfma_kernel(
    const bf16_t* __restrict__ q, const bf16_t* __restrict__ k,
    const bf16_t* __restrict__ vT, bf16_t* __restrict__ attnT)
{
    __shared__ __align__(16) bf16_t As[128 * 32];
    __shared__ __align__(16) bf16_t Bs[128 * 32];
    __shared__ __align__(16) bf16_t S[NT * SLD];

    const int bh = blockIdx.x;
    const int b = bh >> 5, h = bh & 31;
    const bf16_t* Q  = q  + (size_t)bh * NT * NHS;
    const bf16_t* K  = k  + (size_t)bh * NT * NHS;
    const bf16_t* VT = vT + (size_t)bh * NT * NHS;

    const int tid  = threadIdx.x;
    const int lane = tid & 63;
    const int wave = tid >> 6;
    const int wr = (wave >> 1) * 64;
    const int wc = (wave & 1) * 64;
    const int srow = tid >> 2;
    const int scol = (tid & 3) * 8;
    const int m0 = wr + (lane & 15);
    const int n0 = wc + (lane & 15);
    const int kq = (lane >> 4) * 8;
    const int rbase = wr + (lane >> 4) * 4;

    f32x4 acc[4][4] = {};

    // Phase 1: S = scale * Q K^T  (contraction over head-dim, 4 steps of 32)
    for (int k0 = 0; k0 < NHS; k0 += 32) {
        load_lds16(Q + (size_t)srow        * NHS + k0 + scol, &As[srow * 32 + scol]);
        load_lds16(Q + (size_t)(srow + 64) * NHS + k0 + scol, &As[(srow + 64) * 32 + scol]);
        load_lds16(K + (size_t)srow        * NHS + k0 + scol, &Bs[srow * 32 + scol]);
        load_lds16(K + (size_t)(srow + 64) * NHS + k0 + scol, &Bs[(srow + 64) * 32 + scol]);
        __syncthreads();
        bf16x8 af[4], bfr[4];
        #pragma unroll
        for (int i = 0; i < 4; ++i) af[i]  = *(const bf16x8*)&As[(m0 + i * 16) * 32 + kq];
        #pragma unroll
        for (int j = 0; j < 4; ++j) bfr[j] = *(const bf16x8*)&Bs[(n0 + j * 16) * 32 + kq];
        #pragma unroll
        for (int i = 0; i < 4; ++i)
            #pragma unroll
            for (int j = 0; j < 4; ++j)
                acc[i][j] = __builtin_amdgcn_mfma_f32_16x16x32_bf16(af[i], bfr[j], acc[i][j], 0, 0, 0);
        __syncthreads();
    }
    // Store S[t][u] = scale * acc (bf16, ld = SLD)
    #pragma unroll
    for (int i = 0; i < 4; ++i)
        #pragma unroll
        for (int j = 0; j < 4; ++j)
            #pragma unroll
            for (int r = 0; r < 4; ++r)
                S[(rbase + i * 16 + r) * SLD + wc + j * 16 + (lane & 15)] =
                    (bf16_t)(acc[i][j][r] * SCALE);
    __syncthreads();

    // Phase 2: softmax over t (query axis) per column u; single fp32 rounding
    if (tid < NT) {
        const int u = tid;
        float m = -1e30f;
        for (int t = 0; t < NT; ++t) m = fmaxf(m, (float)S[t * SLD + u]);
        float sum = 0.f;
        for (int t = 0; t < NT; ++t) sum += __expf((float)S[t * SLD + u] - m);
        const float inv = 1.0f / sum;
        for (int t = 0; t < NT; ++t)
            S[t * SLD + u] = (bf16_t)(__expf((float)S[t * SLD + u] - m) * inv);
    }
    __syncthreads();

    // Phase 3: O^T[s][t] = sum_u VT[s][u] * P[t][u]; A=VT (global), BT=P (LDS)
    #pragma unroll
    for (int i = 0; i < 4; ++i)
        #pragma unroll
        for (int j = 0; j < 4; ++j)
            acc[i][j] = (f32x4)(0.0f);

    for (int k0 = 0; k0 < NT; k0 += 32) {
        load_lds16(VT + (size_t)srow        * NT + k0 + scol, &As[srow * 32 + scol]);
        load_lds16(VT + (size_t)(srow + 64) * NT + k0 + scol, &As[(srow + 64) * 32 + scol]);
        __syncthreads();
        bf16x8 af[4], bfr[4];
        #pragma unroll
        for (int i = 0; i < 4; ++i) af[i]  = *(const bf16x8*)&As[(m0 + i * 16) * 32 + kq];
        #pragma unroll
        for (int j = 0; j < 4; ++j) bfr[j] = *(const bf16x8*)&S[(n0 + j * 16) * SLD + k0 + kq];
        #pragma unroll
        for (int i = 0; i < 4; ++i)
            #pragma unroll
            for (int j = 0; j < 4; ++j)
                acc[i][j] = __builtin_amdgcn_mfma_f32_16x16x32_bf16(af[i], bfr[j], acc[i][j], 0, 0, 0);
        __syncthreads();
    }
    // Epilogue: D[s][t] -> attnT[b][s][h*T + t]
    bf16_t* AT = attnT + (size_t)b * NHS * NC + h * NT;
    #pragma unroll
    for (int i = 0; i < 4; ++i)
        #pragma unroll
        for (int j = 0; j < 4; ++j)
            #pragma unroll
            for (int r = 0; r < 4; ++r)
                AT[(size_t)(rbase + i * 16 + r) * NC + wc + j * 16 + (lane & 15)] =
                    (bf16_t)acc[i][j][r];
}

// ---------------------------------------------------------------------------
extern "C" void kernel_launch(void* const* d_in, const int* in_sizes, int n_in,
                              void* d_out, int out_size, void* d_ws, size_t ws_size,
                              hipStream_t stream) {
    const float* x  = (const float*)d_in[0];
    const float* wq = (const float*)d_in[1];
    const float* wk = (const float*)d_in[2];
    const float* wv = (const float*)d_in[3];
    const float* wp = (const float*)d_in[4];
    const float* bp = (const float*)d_in[5];
    float* out = (float*)d_out;

    const size_t NX = (size_t)NB * NT * NC;     // 33,554,432
    const size_t NW = (size_t)NH * NC * NHS;    // 16,777,216
    bf16_t* xb  = (bf16_t*)d_ws;
    bf16_t* wqT = xb  + NX;
    bf16_t* wkT = wqT + NW;
    bf16_t* wvT = wkT + NW;   // wqT|wkT|wvT are contiguous = Wcat[12288][4096]
    bf16_t* wpb = wvT + NW;
    bf16_t* qb  = wpb + NW;
    bf16_t* kb  = qb  + NX;
    bf16_t* vb  = kb  + NX;   // holds vT [bh][s][u]
    bf16_t* atT = vb  + NX;   // [8192][4096] == [b][s][e]

    cvt_bf16_kernel<<<(int)(NX / 8 / 256), 256, 0, stream>>>(x, xb, (int)(NX / 8));
    cvt_w_transpose_kernel<<<dim3(4096, 3), 256, 0, stream>>>(wq, wk, wv, wqT, wkT, wvT);
    cvt_bf16_kernel<<<(int)(NW / 8 / 256), 256, 0, stream>>>(wp, wpb, (int)(NW / 8));

    qkv_gemm256_kernel<<<1536, 512, 0, stream>>>(xb, wqT, qb, kb, vb);
    attn_mfma_kernel<<<NB * NH, 256, 0, stream>>>(qb, kb, vb, atT);
    proj_gemm256_kernel<<<512, 512, 0, stream>>>(atT, wpb, bp, out);
}

// Round 4
// 1596.980 us; speedup vs baseline: 1.0597x; 1.0319x over previous
//
#include <hip/hip_runtime.h>
#include <cstddef>
#include <cstdint>

// Problem constants (fixed by reference): B=64, T=128, C=4096, H=32, HS=128
#define NB 64
#define NH 32
#define NT 128
#define NHS 128
#define NC 4096
#define SCALE 0.17677669529663687f  // 32^-0.5
#define SLD 136                      // bf16 leading dim for attention score tile

typedef __bf16 bf16_t;
typedef __bf16 bf16x8 __attribute__((ext_vector_type(8)));
typedef float  f32x4  __attribute__((ext_vector_type(4)));

// Async global->LDS, 16B per lane. LDS dest must be wave-uniform base + lane*16.
__device__ __forceinline__ void load_lds16(const bf16_t* g, bf16_t* l) {
    __builtin_amdgcn_global_load_lds(
        (const __attribute__((address_space(1))) char*)g,
        (__attribute__((address_space(3))) char*)l,
        16, 0, 0);
}

// ---------------------------------------------------------------------------
// Conversion: fp32 -> bf16, 8 elements/thread
// ---------------------------------------------------------------------------
__global__ __launch_bounds__(256) void cvt_bf16_kernel(
    const float* __restrict__ in, bf16_t* __restrict__ out, int n8)
{
    int i = blockIdx.x * 256 + threadIdx.x;
    if (i >= n8) return;
    const float4* p = (const float4*)in + (size_t)i * 2;
    float4 a = p[0], b = p[1];
    bf16x8 o;
    o[0] = (bf16_t)a.x; o[1] = (bf16_t)a.y; o[2] = (bf16_t)a.z; o[3] = (bf16_t)a.w;
    o[4] = (bf16_t)b.x; o[5] = (bf16_t)b.y; o[6] = (bf16_t)b.z; o[7] = (bf16_t)b.w;
    ((bf16x8*)out)[i] = o;
}

// ---------------------------------------------------------------------------
// Conversion + transpose: w [H][C][HS] fp32 -> wT [H][HS][C] bf16.
// ---------------------------------------------------------------------------
__global__ __launch_bounds__(256) void cvt_w_transpose_kernel(
    const float* __restrict__ wq, const float* __restrict__ wk, const float* __restrict__ wv,
    bf16_t* __restrict__ qt, bf16_t* __restrict__ kt, bf16_t* __restrict__ vt)
{
    const float* w; bf16_t* o;
    if (blockIdx.y == 0)      { w = wq; o = qt; }
    else if (blockIdx.y == 1) { w = wk; o = kt; }
    else                      { w = wv; o = vt; }
    const int h   = blockIdx.x >> 7;
    const int rem = blockIdx.x & 127;
    const int c0  = (rem >> 1) * 64;
    const int s0  = (rem & 1) * 64;
    const float* W = w + (size_t)h * NC * NHS;
    bf16_t* O = o + (size_t)h * NHS * NC;

    __shared__ float t[64][65];
    const int tid = threadIdx.x;
    #pragma unroll
    for (int it = 0; it < 16; ++it) {
        int idx = it * 256 + tid;
        int r = idx >> 6, cc = idx & 63;
        t[r][cc] = W[(size_t)(c0 + r) * NHS + s0 + cc];
    }
    __syncthreads();
    #pragma unroll
    for (int it = 0; it < 16; ++it) {
        int idx = it * 256 + tid;
        int sr = idx >> 6, cr = idx & 63;
        O[(size_t)(s0 + sr) * NC + c0 + cr] = (bf16_t)t[cr][sr];
    }
}

// ---------------------------------------------------------------------------
// 256x256 tile GEMM core, K = 4096 (ld = NC), 8 waves, BK = 64.
// Fine-grained 4-phase schedule per K-tile (m201/T3+T4 mechanism):
//   each phase = { ds_read frags , stage ONE half-tile , barrier ,
//                  lgkmcnt(0) , setprio(1) , 16 MFMA , setprio(0) , barrier }
// A ring-of-3 (96 KB) + B ring-of-2 (64 KB) = 160 KB LDS -> staging for tile
// t+1 (B) / t+2 (A) always targets a region freed at end of tile t-1, so
// vmcnt stays counted (4) in steady state -- never drained to 0 in the loop.
// XOR-swizzled LDS via pre-swizzled global source (zero bank conflicts, r2).
// ---------------------------------------------------------------------------
#define KT_EL 16384   // K-tile elements: 256 rows x 64 cols

__device__ __forceinline__ void gemm256_core(
    const bf16_t* __restrict__ A, const bf16_t* __restrict__ BT, f32x4 acc[8][4])
{
    __shared__ __align__(16) bf16_t As[3 * KT_EL];   // 96 KB, ring of 3
    __shared__ __align__(16) bf16_t Bs[2 * KT_EL];   // 64 KB, ring of 2

    const int tid  = threadIdx.x;
    const int lane = tid & 63;
    const int w    = tid >> 6;
    const int wr   = w >> 2;   // 0..1 (M half)
    const int wc   = w & 3;    // 0..3 (N quarter)

    // staging geometry: slab j (64 rows), thread covers 8 contiguous els.
    // LDS filled LINEARLY; global source column pre-swizzled so LDS slot
    // (r,c) holds element (r, c ^ ((r&7)<<3)) -> conflict-free ds_read_b128.
    const int srow  = tid >> 3;                                   // 0..63
    const int scol  = ((tid & 7) * 8) ^ (((tid >> 3) & 7) << 3);  // pre-swizzled
    const int sslot = tid * 8;                                    // elements

    // fragment read offsets (elements within one 16384-el K-tile)
    const int frow = lane & 15;
    const int fk   = (lane >> 4) * 8;
    int aoff[2][2][4];   // [ks][ih][q] : row = wr*128 + ih*64 + q*16 + frow
    #pragma unroll
    for (int ks = 0; ks < 2; ++ks)
        #pragma unroll
        for (int ih = 0; ih < 2; ++ih)
            #pragma unroll
            for (int q = 0; q < 4; ++q) {
                int r = wr * 128 + ih * 64 + q * 16 + frow;
                aoff[ks][ih][q] = r * 64 + ((ks * 32 + fk) ^ ((r & 7) << 3));
            }
    int boff[2][4];      // [ks][n] : row = wc*64 + n*16 + frow
    #pragma unroll
    for (int ks = 0; ks < 2; ++ks)
        #pragma unroll
        for (int n = 0; n < 4; ++n) {
            int r = wc * 64 + n * 16 + frow;
            boff[ks][n] = r * 64 + ((ks * 32 + fk) ^ ((r & 7) << 3));
        }

    // stage one half-tile (128 rows = slabs {2h, 2h+1}), 2 loads/thread
    auto stageH = [&](const bf16_t* __restrict__ G, int half, int k0, bf16_t* dst) {
        #pragma unroll
        for (int jj = 0; jj < 2; ++jj) {
            const int j = half * 2 + jj;
            load_lds16(G + (size_t)(j * 64 + srow) * NC + (k0 + scol),
                       dst + j * 4096 + sslot);
        }
    };

    // Prologue: B(0)->Bbuf0, A(0)->slot0, A(1)->slot1  (12 loads/thread).
    stageH(BT, 0, 0, Bs);          stageH(BT, 1, 0, Bs);
    stageH(A,  0, 0, As);          stageH(A,  1, 0, As);
    stageH(A,  0, 64, As + KT_EL); stageH(A,  1, 64, As + KT_EL);
    asm volatile("s_waitcnt vmcnt(4)" ::: "memory");   // B(0),A(0) resident; A(1) in flight
    __builtin_amdgcn_s_barrier();
    __builtin_amdgcn_sched_barrier(0);

    int a_cur = 0;   // A ring slot of tile t
    #pragma unroll 1
    for (int t = 0; t < NC / 64; ++t) {
        bf16_t* Ac = As + a_cur * KT_EL;
        bf16_t* Bc = Bs + (t & 1) * KT_EL;
        bf16_t* Bn = Bs + ((t + 1) & 1) * KT_EL;
        const int a_n2 = (a_cur >= 1) ? a_cur - 1 : 2;   // (t+2) % 3
        bf16_t* An = As + a_n2 * KT_EL;
        const bool pfB = (t < NC / 64 - 1);
        const bool pfA = (t < NC / 64 - 2);
        const int kB = (t + 1) * 64;
        const int kA = (t + 2) * 64;

        bf16x8 a[4], b0[4], b1[4];

        // ---- phase 1: b0 + a(ih0,ks0) reads; stage B(t+1) half0 ----
        #pragma unroll
        for (int n = 0; n < 4; ++n) b0[n] = *(const bf16x8*)(Bc + boff[0][n]);
        #pragma unroll
        for (int q = 0; q < 4; ++q) a[q] = *(const bf16x8*)(Ac + aoff[0][0][q]);
        if (pfB) stageH(BT, 0, kB, Bn);
        __builtin_amdgcn_sched_barrier(0);
        __builtin_amdgcn_s_barrier();
        asm volatile("s_waitcnt lgkmcnt(0)" ::: "memory");
        __builtin_amdgcn_sched_barrier(0);
        __builtin_amdgcn_s_setprio(1);
        #pragma unroll
        for (int q = 0; q < 4; ++q)
            #pragma unroll
            for (int n = 0; n < 4; ++n)
                acc[q][n] = __builtin_amdgcn_mfma_f32_16x16x32_bf16(a[q], b0[n], acc[q][n], 0, 0, 0);
        __builtin_amdgcn_s_setprio(0);
        __builtin_amdgcn_s_barrier();
        __builtin_amdgcn_sched_barrier(0);

        // ---- phase 2: a(ih1,ks0) reads; stage B(t+1) half1 ----
        #pragma unroll
        for (int q = 0; q < 4; ++q) a[q] = *(const bf16x8*)(Ac + aoff[0][1][q]);
        if (pfB) stageH(BT, 1, kB, Bn);
        __builtin_amdgcn_sched_barrier(0);
        __builtin_amdgcn_s_barrier();
        asm volatile("s_waitcnt lgkmcnt(0)" ::: "memory");
        __builtin_amdgcn_sched_barrier(0);
        __builtin_amdgcn_s_setprio(1);
        #pragma unroll
        for (int q = 0; q < 4; ++q)
            #pragma unroll
            for (int n = 0; n < 4; ++n)
                acc[4 + q][n] = __builtin_amdgcn_mfma_f32_16x16x32_bf16(a[q], b0[n], acc[4 + q][n], 0, 0, 0);
        __builtin_amdgcn_s_setprio(0);
        __builtin_amdgcn_s_barrier();
        __builtin_amdgcn_sched_barrier(0);

        // ---- phase 3: b1 + a(ih0,ks1) reads; stage A(t+2) half0 ----
        #pragma unroll
        for (int n = 0; n < 4; ++n) b1[n] = *(const bf16x8*)(Bc + boff[1][n]);
        #pragma unroll
        for (int q = 0; q < 4; ++q) a[q] = *(const bf16x8*)(Ac + aoff[1][0][q]);
        if (pfA) stageH(A, 0, kA, An);
        __builtin_amdgcn_sched_barrier(0);
        __builtin_amdgcn_s_barrier();
        asm volatile("s_waitcnt lgkmcnt(0)" ::: "memory");
        __builtin_amdgcn_sched_barrier(0);
        __builtin_amdgcn_s_setprio(1);
        #pragma unroll
        for (int q = 0; q < 4; ++q)
            #pragma unroll
            for (int n = 0; n < 4; ++n)
                acc[q][n] = __builtin_amdgcn_mfma_f32_16x16x32_bf16(a[q], b1[n], acc[q][n], 0, 0, 0);
        __builtin_amdgcn_s_setprio(0);
        __builtin_amdgcn_s_barrier();
        __builtin_amdgcn_sched_barrier(0);

        // ---- phase 4: a(ih1,ks1) reads; stage A(t+2) half1; counted vmcnt ----
        #pragma unroll
        for (int q = 0; q < 4; ++q) a[q] = *(const bf16x8*)(Ac + aoff[1][1][q]);
        if (pfA) {
            stageH(A, 1, kA, An);
            // retire tile t+1 (B staged phases 1-2, A staged during t-1);
            // keep A(t+2)'s 4 loads in flight.
            asm volatile("s_waitcnt vmcnt(4)" ::: "memory");
        } else if (pfB) {          // t == 62: drain tail so B(63) is resident
            asm volatile("s_waitcnt vmcnt(0)" ::: "memory");
        }
        __builtin_amdgcn_sched_barrier(0);
        __builtin_amdgcn_s_barrier();
        asm volatile("s_waitcnt lgkmcnt(0)" ::: "memory");
        __builtin_amdgcn_sched_barrier(0);
        __builtin_amdgcn_s_setprio(1);
        #pragma unroll
        for (int q = 0; q < 4; ++q)
            #pragma unroll
            for (int n = 0; n < 4; ++n)
                acc[4 + q][n] = __builtin_amdgcn_mfma_f32_16x16x32_bf16(a[q], b1[n], acc[4 + q][n], 0, 0, 0);
        __builtin_amdgcn_s_setprio(0);
        __builtin_amdgcn_s_barrier();
        __builtin_amdgcn_sched_barrier(0);

        a_cur = (a_cur == 2) ? 0 : a_cur + 1;
    }
}

// ---------------------------------------------------------------------------
// QKV as ONE GEMM: x[8192,4096] * Wcat[12288,4096]^T.  Wcat = wqT|wkT|wvT
// contiguous ([tensor][h][s][c]).  grid = 1536 blocks (32 mt x 48 nt),
// XCD-chunked swizzle.  q,k stored [bh][t][s]; v stored transposed [bh][s][t].
// ---------------------------------------------------------------------------
__global__ __launch_bounds__(512, 2) void qkv_gemm256_kernel(
    const bf16_t* __restrict__ xb, const bf16_t* __restrict__ wcat,
    bf16_t* __restrict__ q, bf16_t* __restrict__ k, bf16_t* __restrict__ v)
{
    const int bid = blockIdx.x;
    const int wg  = (bid & 7) * 192 + (bid >> 3);   // 1536 = 8 * 192, bijective
    const int mt  = wg / 48;
    const int nt  = wg - mt * 48;
    const int Mb  = mt << 8;
    const int Nb  = nt << 8;

    f32x4 acc[8][4] = {};
    gemm256_core(xb + (size_t)Mb * NC, wcat + (size_t)Nb * NC, acc);

    const int tid = threadIdx.x, lane = tid & 63, w = tid >> 6;
    const int wr = w >> 2, wc = w & 3;
    const int tens = Nb >> 12;                       // 0=q 1=k 2=v (uniform)
    bf16_t* const outp = (tens == 0) ? q : (tens == 1) ? k : v;
    const int colb = Nb + wc * 64 + (lane & 15);
    const int rowb = Mb + wr * 128 + ((lane >> 4) << 2);
    #pragma unroll
    for (int i = 0; i < 8; ++i)
        #pragma unroll
        for (int r = 0; r < 4; ++r) {
            const int m  = rowb + i * 16 + r;
            const int bb = m >> 7, tt = m & 127;
            #pragma unroll
            for (int n = 0; n < 4; ++n) {
                const int ng = colb + n * 16;
                const int hh = (ng >> 7) & 31, ss = ng & 127;
                const size_t base = (size_t)((bb << 5) + hh) << 14;
                if (tens == 2) outp[base + ss * NT  + tt] = (bf16_t)acc[i][n][r];
                else           outp[base + tt * NHS + ss] = (bf16_t)acc[i][n][r];
            }
        }
}

// ---------------------------------------------------------------------------
// Projection as ONE GEMM: attnT[8192,4096] * wp[4096,4096]^T + bp.
// grid = 512 blocks (32 mt x 16 nt), XCD-chunked swizzle.
// ---------------------------------------------------------------------------
__global__ __launch_bounds__(512, 2) void proj_gemm256_kernel(
    const bf16_t* __restrict__ attnT, const bf16_t* __restrict__ wpb,
    const float* __restrict__ bp, float* __restrict__ out)
{
    const int bid = blockIdx.x;
    const int wg  = (bid & 7) * 64 + (bid >> 3);    // 512 = 8 * 64, bijective
    const int mt  = wg >> 4;
    const int nt  = wg & 15;
    const int Mb  = mt << 8;
    const int Nb  = nt << 8;

    f32x4 acc[8][4] = {};
    gemm256_core(attnT + (size_t)Mb * NC, wpb + (size_t)Nb * NC, acc);

    const int tid = threadIdx.x, lane = tid & 63, w = tid >> 6;
    const int wr = w >> 2, wc = w & 3;
    const int colb = Nb + wc * 64 + (lane & 15);
    const int rowb = Mb + wr * 128 + ((lane >> 4) << 2);
    float bias[4];
    #pragma unroll
    for (int n = 0; n < 4; ++n) bias[n] = bp[colb + n * 16];
    #pragma unroll
    for (int i = 0; i < 8; ++i)
        #pragma unroll
        for (int r = 0; r < 4; ++r) {
            const size_t m = (size_t)(rowb + i * 16 + r);
            #pragma unroll
            for (int n = 0; n < 4; ++n)
                out[m * NC + colb + n * 16] = acc[i][n][r] + bias[n];
        }
}

// ---------------------------------------------------------------------------
// MFMA attention per (b,h): S = scale*Q*K^T (MFMA) -> column softmax (query
// axis, fp32) -> O^T[s][t] = sum_u vT[s][u] * P[t][u] (MFMA).
// Writes attnT[b][s][h*T+t] bf16. LDS: 8K As + 8K Bs + 34K S = 50 KB.
// ---------------------------------------------------------------------------
__global__ __launch_bounds__(256) void attn_mfma_kernel(
    const bf16_t* __restrict__ q, const bf16_t* __restrict__ k,
    const bf16_t* __restrict__ vT, bf16_t* __restrict__ attnT)
{
    __shared__ __align__(16) bf16_t As[128 * 32];
    __shared__ __align__(16) bf16_t Bs[128 * 32];
    __shared__ __align__(16) bf16_t S[NT * SLD];

    const int bh = blockIdx.x;
    const int b = bh >> 5, h = bh & 31;
    const bf16_t* Q  = q  + (size_t)bh * NT * NHS;
    const bf16_t* K  = k  + (size_t)bh * NT * NHS;
    const bf16_t* VT = vT + (size_t)bh * NT * NHS;

    const int tid  = threadIdx.x;
    const int lane = tid & 63;
    const int wave = tid >> 6;
    const int wr = (wave >> 1) * 64;
    const int wc = (wave & 1) * 64;
    const int srow = tid >> 2;
    const int scol = (tid & 3) * 8;
    const int m0 = wr + (lane & 15);
    const int n0 = wc + (lane & 15);
    const int kq = (lane >> 4) * 8;
    const int rbase = wr + (lane >> 4) * 4;

    f32x4 acc[4][4] = {};

    // Phase 1: S = scale * Q K^T  (contraction over head-dim, 4 steps of 32)
    for (int k0 = 0; k0 < NHS; k0 += 32) {
        load_lds16(Q + (size_t)srow        * NHS + k0 + scol, &As[srow * 32 + scol]);
        load_lds16(Q + (size_t)(srow + 64) * NHS + k0 + scol, &As[(srow + 64) * 32 + scol]);
        load_lds16(K + (size_t)srow        * NHS + k0 + scol, &Bs[srow * 32 + scol]);
        load_lds16(K + (size_t)(srow + 64) * NHS + k0 + scol, &Bs[(srow + 64) * 32 + scol]);
        __syncthreads();
        bf16x8 af[4], bfr[4];
        #pragma unroll
        for (int i = 0; i < 4; ++i) af[i]  = *(const bf16x8*)&As[(m0 + i * 16) * 32 + kq];
        #pragma unroll
        for (int j = 0; j < 4; ++j) bfr[j] = *(const bf16x8*)&Bs[(n0 + j * 16) * 32 + kq];
        #pragma unroll
        for (int i = 0; i < 4; ++i)
            #pragma unroll
            for (int j = 0; j < 4; ++j)
                acc[i][j] = __builtin_amdgcn_mfma_f32_16x16x32_bf16(af[i], bfr[j], acc[i][j], 0, 0, 0);
        __syncthreads();
    }
    // Store S[t][u] = scale * acc (bf16, ld = SLD)
    #pragma unroll
    for (int i = 0; i < 4; ++i)
        #pragma unroll
        for (int j = 0; j < 4; ++j)
            #pragma unroll
            for (int r = 0; r < 4; ++r)
                S[(rbase + i * 16 + r) * SLD + wc + j * 16 + (lane & 15)] =
                    (bf16_t)(acc[i][j][r] * SCALE);
    __syncthreads();

    // Phase 2: softmax over t (query axis) per column u; single fp32 rounding
    if (tid < NT) {
        const int u = tid;
        float m = -1e30f;
        for (int t = 0; t < NT; ++t) m = fmaxf(m, (float)S[t * SLD + u]);
        float sum = 0.f;
        for (int t = 0; t < NT; ++t) sum += __expf((float)S[t * SLD + u] - m);
        const float inv = 1.0f / sum;
        for (int t = 0; t < NT; ++t)
            S[t * SLD + u] = (bf16_t)(__expf((float)S[t * SLD + u] - m) * inv);
    }
    __syncthreads();

    // Phase 3: O^T[s][t] = sum_u VT[s][u] * P[t][u]; A=VT (global), BT=P (LDS)
    #pragma unroll
    for (int i = 0; i < 4; ++i)
        #pragma unroll
        for (int j = 0; j < 4; ++j)
            acc[i][j] = (f32x4)(0.0f);

    for (int k0 = 0; k0 < NT; k0 += 32) {
        load_lds16(VT + (size_t)srow        * NT + k0 + scol, &As[srow * 32 + scol]);
        load_lds16(VT + (size_t)(srow + 64) * NT + k0 + scol, &As[(srow + 64) * 32 + scol]);
        __syncthreads();
        bf16x8 af[4], bfr[4];
        #pragma unroll
        for (int i = 0; i < 4; ++i) af[i]  = *(const bf16x8*)&As[(m0 + i * 16) * 32 + kq];
        #pragma unroll
        for (int j = 0; j < 4; ++j) bfr[j] = *(const bf16x8*)&S[(n0 + j * 16) * SLD + k0 + kq];
        #pragma unroll
        for (int i = 0; i < 4; ++i)
            #pragma unroll
            for (int j = 0; j < 4; ++j)
                acc[i][j] = __builtin_amdgcn_mfma_f32_16x16x32_bf16(af[i], bfr[j], acc[i][j], 0, 0, 0);
        __syncthreads();
    }
    // Epilogue: D[s][t] -> attnT[b][s][h*T + t]
    bf16_t* AT = attnT + (size_t)b * NHS * NC + h * NT;
    #pragma unroll
    for (int i = 0; i < 4; ++i)
        #pragma unroll
        for (int j = 0; j < 4; ++j)
            #pragma unroll
            for (int r = 0; r < 4; ++r)
                AT[(size_t)(rbase + i * 16 + r) * NC + wc + j * 16 + (lane & 15)] =
                    (bf16_t)acc[i][j][r];
}

// ---------------------------------------------------------------------------
extern "C" void kernel_launch(void* const* d_in, const int* in_sizes, int n_in,
                              void* d_out, int out_size, void* d_ws, size_t ws_size,
                              hipStream_t stream) {
    const float* x  = (const float*)d_in[0];
    const float* wq = (const float*)d_in[1];
    const float* wk = (const float*)d_in[2];
    const float* wv = (const float*)d_in[3];
    const float* wp = (const float*)d_in[4];
    const float* bp = (const float*)d_in[5];
    float* out = (float*)d_out;

    const size_t NX = (size_t)NB * NT * NC;     // 33,554,432
    const size_t NW = (size_t)NH * NC * NHS;    // 16,777,216
    bf16_t* xb  = (bf16_t*)d_ws;
    bf16_t* wqT = xb  + NX;
    bf16_t* wkT = wqT + NW;
    bf16_t* wvT = wkT + NW;   // wqT|wkT|wvT are contiguous = Wcat[12288][4096]
    bf16_t* wpb = wvT + NW;
    bf16_t* qb  = wpb + NW;
    bf16_t* kb  = qb  + NX;
    bf16_t* vb  = kb  + NX;   // holds vT [bh][s][u]
    bf16_t* atT = vb  + NX;   // [8192][4096] == [b][s][e]

    cvt_bf16_kernel<<<(int)(NX / 8 / 256), 256, 0, stream>>>(x, xb, (int)(NX / 8));
    cvt_w_transpose_kernel<<<dim3(4096, 3), 256, 0, stream>>>(wq, wk, wv, wqT, wkT, wvT);
    cvt_bf16_kernel<<<(int)(NW / 8 / 256), 256, 0, stream>>>(wp, wpb, (int)(NW / 8));

    qkv_gemm256_kernel<<<1536, 512, 0, stream>>>(xb, wqT, qb, kb, vb);
    attn_mfma_kernel<<<NB * NH, 256, 0, stream>>>(qb, kb, vb, atT);
    proj_gemm256_kernel<<<512, 512, 0, stream>>>(atT, wpb, bp, out);
}